// Round 5
// baseline (508.308 us; speedup 1.0000x reference)
//
#include <hip/hip_runtime.h>
#include <hip/hip_bf16.h>
#include <math.h>

#define B_ 4
#define L_ 4096
#define D_ 1024
#define M_ (B_*L_)     // 16384
#define N_ 5120        // psi_re | psi_im | phi_re | phi_im | gate (1024 each)
#define K_ 1024
#define CHUNKS 128
#define LC 32          // L_ / CHUNKS
#define PL ((long)M_ * D_)   // plane elements = 16,777,216

// ws layout (bytes):
//   [0        , 33554432)  xb (bf16 x)              -- dead after GEMM
//   [33554432 , 44040192)  wb (bf16 W concat)       -- dead after GEMM
//   [44040192 , 211812352) raw5: 5 bf16 planes [g][M][D]
//       planes: 0=psi_re->H_re  1=psi_im->H_im  2=phi_re  3=phi_im  4=gate
//   overlay after GEMM (inside dead xb region):
//       E at [0, 4194304), carry at [4194304, 8388608), apow at [8388608, 8650752)
#define WS_NEEDED 211812352ull

typedef __attribute__((ext_vector_type(8))) short bf16x8;
typedef __attribute__((ext_vector_type(4))) float f32x4;
typedef __attribute__((ext_vector_type(2))) unsigned long long u64x2;

__device__ inline float b2f(unsigned short s) {
    unsigned u = ((unsigned)s) << 16;
    float f; __builtin_memcpy(&f, &u, 4); return f;
}
__device__ inline unsigned short f2b(float f) {
    __hip_bfloat16 h = __float2bfloat16(f);
    unsigned short s; __builtin_memcpy(&s, &h, 2); return s;
}

// ---------------- K0: convert x and concat(W_psi, W_phi, W_gate) to bf16 (vectorized) ----
__device__ inline void cvt4(const float4* __restrict__ src, ushort* __restrict__ dst, long j) {
    float4 v = src[j];
    ushort4 o = { f2b(v.x), f2b(v.y), f2b(v.z), f2b(v.w) };
    *(ushort4*)(dst + j * 4) = o;
}

__global__ void convert_kernel(const float* __restrict__ x,
                               const float* __restrict__ Wpsi,
                               const float* __restrict__ Wphi,
                               const float* __restrict__ Wgate,
                               ushort* __restrict__ xb,
                               ushort* __restrict__ wb) {
    long i0 = (long)blockIdx.x * blockDim.x + threadIdx.x;
    long stride = (long)gridDim.x * blockDim.x;
    const long nx4 = ((long)M_ * K_) >> 2;           // 4,194,304
    for (long j = i0; j < nx4; j += stride) cvt4((const float4*)x, xb, j);
    const long nW14 = (2048L * 1024) >> 2, nW34 = (1024L * 1024) >> 2;
    for (long j = i0; j < nW14; j += stride) cvt4((const float4*)Wpsi, wb, j);
    for (long j = i0; j < nW14; j += stride) cvt4((const float4*)Wphi, wb + 2048L * 1024, j);
    for (long j = i0; j < nW34; j += stride) cvt4((const float4*)Wgate, wb + 4096L * 1024, j);
}

// ---------------- K1: bf16 MFMA GEMM, LDS-staged, LDS-repacked epilogue ----------------
#define BM 128
#define BN 128
#define BK 64
// Repack region: per wave 64 rows x 136 B (64 bf16 + 8 B pad) = 8704 B; 4 waves = 34816 B.
// Stride 136: quad write offsets 4*136 B apart = 8 banks apart -> 4 quads cover all 32 banks,
// 2 lanes/bank (free). 8-B alignment allows ds_read_b64 readback.
#define CROW 136
__global__ __launch_bounds__(256) void gemm_kernel(const __hip_bfloat16* __restrict__ xb,
                                                   const __hip_bfloat16* __restrict__ wb,
                                                   const float* __restrict__ b_psi,
                                                   const float* __restrict__ b_phi,
                                                   const float* __restrict__ b_gate,
                                                   __hip_bfloat16* __restrict__ raw5) {
    __shared__ __align__(16) char smem[4 * 64 * CROW];   // 34816 B >= 32768 staging
    __hip_bfloat16* As = (__hip_bfloat16*)smem;          // 16 KB
    __hip_bfloat16* Bs = (__hip_bfloat16*)(smem + 16384);

    const int tid  = threadIdx.x;
    const int wave = tid >> 6;
    const int lane = tid & 63;
    const int row16 = lane & 15;
    const int quad  = lane >> 4;
    const int m_blk = blockIdx.x * BM;
    const int n_blk = blockIdx.y * BN;
    const int m_off = (wave >> 1) * 64;
    const int n_off = (wave & 1) * 64;

    const int sub_r = lane >> 3;   // 0..7
    const int ci    = lane & 7;    // LDS chunk position within row

    f32x4 acc[4][4] = {};

    for (int k0 = 0; k0 < K_; k0 += BK) {
        __syncthreads();
#pragma unroll
        for (int j2 = 0; j2 < 4; j2++) {
            int j  = wave * 4 + j2;
            int r  = j * 8 + sub_r;
            int gc = ci ^ (r & 7);
            const __hip_bfloat16* ga = xb + (long)(m_blk + r) * K_ + k0 + gc * 8;
            const __hip_bfloat16* gb = wb + (long)(n_blk + r) * K_ + k0 + gc * 8;
            __builtin_amdgcn_global_load_lds(
                (const __attribute__((address_space(1))) void*)ga,
                (__attribute__((address_space(3))) void*)((char*)As + j * 1024),
                16, 0, 0);
            __builtin_amdgcn_global_load_lds(
                (const __attribute__((address_space(1))) void*)gb,
                (__attribute__((address_space(3))) void*)((char*)Bs + j * 1024),
                16, 0, 0);
        }
        __syncthreads();

#pragma unroll
        for (int ks = 0; ks < 2; ks++) {
            bf16x8 a[4], b[4];
            int c = ks * 4 + quad;
#pragma unroll
            for (int t = 0; t < 4; t++) {
                int ra = m_off + t * 16 + row16;
                a[t] = *(const bf16x8*)((const char*)As + ra * 128 + ((c ^ (ra & 7)) * 16));
                int rb = n_off + t * 16 + row16;
                b[t] = *(const bf16x8*)((const char*)Bs + rb * 128 + ((c ^ (rb & 7)) * 16));
            }
#pragma unroll
            for (int mi = 0; mi < 4; mi++)
#pragma unroll
                for (int ni = 0; ni < 4; ni++)
                    acc[mi][ni] = __builtin_amdgcn_mfma_f32_16x16x32_bf16(a[mi], b[ni], acc[mi][ni], 0, 0, 0);
        }
    }

    // ---- epilogue: bias + bf16 cvt -> LDS repack -> full-line global stores ----
    __syncthreads();                       // all waves done reading As/Bs
    char* cbase = smem + wave * (64 * CROW);
    const int nb = n_blk + n_off;          // wave's 64-col range, within one plane
#pragma unroll
    for (int ni = 0; ni < 4; ni++) {
        int n = nb + ni * 16 + row16;
        float bias = (n < 2048) ? b_psi[n] : (n < 4096) ? b_phi[n - 2048] : b_gate[n - 4096];
        int nc = ni * 16 + row16;
#pragma unroll
        for (int mi = 0; mi < 4; mi++) {
#pragma unroll
            for (int r = 0; r < 4; r++) {
                int mr = mi * 16 + quad * 4 + r;
                *(unsigned short*)(cbase + mr * CROW + nc * 2) = f2b(acc[mi][ni][r] + bias);
            }
        }
    }
    __syncthreads();                       // wave-internal visibility (and cheap)

    const int g  = nb >> 10;
    const int d0 = nb & 1023;
    const int m  = m_blk + m_off + lane;
    char* gout = (char*)(raw5 + (long)g * PL + (long)m * D_ + d0);   // 128-B aligned
    const char* crow = cbase + lane * CROW;                           // 8-B aligned
#pragma unroll
    for (int q = 0; q < 8; q++) {
        unsigned long long lo = *(const unsigned long long*)(crow + q * 16);
        unsigned long long hi = *(const unsigned long long*)(crow + q * 16 + 8);
        u64x2 v = { lo, hi };
        *(u64x2*)(gout + q * 16) = v;
    }
}

// ---------------- K2: local scan (gate fused), 4 channels/thread, in-place over psi ----
__global__ __launch_bounds__(256) void scan1_kernel(__hip_bfloat16* raw5,   // in-place
                                                    const float* __restrict__ omega,
                                                    const float* __restrict__ log_gamma,
                                                    const float* __restrict__ dtp,
                                                    float2* __restrict__ E) {
    const int d0 = threadIdx.x * 4;
    const int c = blockIdx.x;
    const int b = blockIdx.y;
    const float dt = fabsf(dtp[0]);

    float ar[4], ai[4], hr[4] = {0.f,0.f,0.f,0.f}, hi[4] = {0.f,0.f,0.f,0.f};
#pragma unroll
    for (int j = 0; j < 4; j++) {
        float decay = expf(-expf(log_gamma[d0 + j]) * dt);
        float ang = omega[d0 + j] * dt;
        ar[j] = decay * cosf(ang); ai[j] = decay * sinf(ang);
    }

    ushort* Pre = (ushort*)raw5;
    ushort* Pim = (ushort*)(raw5 + PL);
    const ushort* Gt = (const ushort*)(raw5 + 4 * PL);
    long base = (long)(b * L_ + c * LC) * D_ + d0;

    for (int i = 0; i < LC; i++) {
        long idx = base + (long)i * D_;
        ushort4 gv = *(const ushort4*)(Gt + idx);
        ushort4 rv = *(const ushort4*)(Pre + idx);
        ushort4 iv = *(const ushort4*)(Pim + idx);
        float gs[4] = { b2f(gv.x), b2f(gv.y), b2f(gv.z), b2f(gv.w) };
        float ur[4] = { b2f(rv.x), b2f(rv.y), b2f(rv.z), b2f(rv.w) };
        float ui[4] = { b2f(iv.x), b2f(iv.y), b2f(iv.z), b2f(iv.w) };
#pragma unroll
        for (int j = 0; j < 4; j++) {
            float sg = 1.f / (1.f + expf(-gs[j]));
            float nhr = ar[j] * hr[j] - ai[j] * hi[j] + sg * ur[j];
            float nhi = ar[j] * hi[j] + ai[j] * hr[j] + sg * ui[j];
            hr[j] = nhr; hi[j] = nhi;
        }
        ushort4 ro = { f2b(hr[0]), f2b(hr[1]), f2b(hr[2]), f2b(hr[3]) };
        ushort4 io = { f2b(hi[0]), f2b(hi[1]), f2b(hi[2]), f2b(hi[3]) };
        *(ushort4*)(Pre + idx) = ro;
        *(ushort4*)(Pim + idx) = io;
    }
    float2* Ep = E + ((long)c * B_ + b) * D_ + d0;
#pragma unroll
    for (int j = 0; j < 4; j++) Ep[j] = make_float2(hr[j], hi[j]);
}

// ---------------- K3: Apow[i][d] = a_d^(i+1) ----------------
__global__ void apow_kernel(const float* __restrict__ omega,
                            const float* __restrict__ log_gamma,
                            const float* __restrict__ dtp,
                            float2* __restrict__ apow) {
    int t = blockIdx.x * blockDim.x + threadIdx.x;  // 0..32767
    int i = t >> 10, d = t & 1023;
    float dt = fabsf(dtp[0]);
    float e = expf(-expf(log_gamma[d]) * dt * (float)(i + 1));
    float ang = omega[d] * dt * (float)(i + 1);
    apow[t] = make_float2(e * cosf(ang), e * sinf(ang));
}

// ---------------- K4: carry via Kogge-Stone over chunks (one block per (b,d)) --------
__global__ __launch_bounds__(128) void carry_kernel(const float2* __restrict__ E,
                                                    const float* __restrict__ omega,
                                                    const float* __restrict__ log_gamma,
                                                    const float* __restrict__ dtp,
                                                    float2* __restrict__ carry) {
    __shared__ float2 sh[CHUNKS];
    const int c = threadIdx.x;
    const int bd = blockIdx.x;           // b*1024 + d
    const int b = bd >> 10, d = bd & 1023;
    const float dt = fabsf(dtp[0]);
    const float gd = expf(log_gamma[d]);
    const float wd = omega[d];

    float2 v = E[((long)c * B_ + b) * D_ + d];
    sh[c] = v;
    __syncthreads();
#pragma unroll
    for (int s = 1; s < CHUNKS; s <<= 1) {
        float2 prev;
        bool has = (c >= s);
        if (has) prev = sh[c - s];
        __syncthreads();
        if (has) {
            float t = dt * (float)LC * (float)s;
            float dec = expf(-gd * t);
            float ang = wd * t;
            float Ar = dec * cosf(ang), Ai = dec * sinf(ang);
            v.x += Ar * prev.x - Ai * prev.y;
            v.y += Ar * prev.y + Ai * prev.x;
            sh[c] = v;
        }
        __syncthreads();
    }
    float2 outv = (c == 0) ? make_float2(0.f, 0.f) : sh[c - 1];  // carry[c] = t_{c-1}
    carry[((long)c * B_ + b) * D_ + d] = outv;
}

// ---------------- K5: fixup + standardize + output (one wave per row, no barriers) ----
__global__ __launch_bounds__(256) void finish_kernel(const __hip_bfloat16* __restrict__ raw5,
                                                     const float2* __restrict__ carry,
                                                     const float2* __restrict__ apow,
                                                     float* __restrict__ out) {
    const int wv = threadIdx.x >> 6, lane = threadIdx.x & 63;
    const int r = blockIdx.x * 4 + wv;       // row 0..16383
    const int l = r & (L_ - 1);
    const int b = r >> 12;
    const int c = l >> 5, i = l & 31;
    const int d0 = lane * 16;
    const long base = (long)r * D_ + d0;

    const __hip_bfloat16* Hre = raw5;
    const __hip_bfloat16* Him = raw5 + PL;
    const __hip_bfloat16* Pre = raw5 + 2 * PL;
    const __hip_bfloat16* Pim = raw5 + 3 * PL;
    const float2* cr = carry + ((long)c * B_ + b) * D_ + d0;
    const float2* ap = apow + (long)i * D_ + d0;

    bf16x8 hre[2], him[2];
    hre[0] = *(const bf16x8*)(Hre + base);     hre[1] = *(const bf16x8*)(Hre + base + 8);
    him[0] = *(const bf16x8*)(Him + base);     him[1] = *(const bf16x8*)(Him + base + 8);

    float hr[16], hi[16];
    float s0 = 0.f, s1 = 0.f, s2 = 0.f, s3 = 0.f;
#pragma unroll
    for (int j = 0; j < 16; j++) {
        float2 cv = cr[j];
        float2 av = ap[j];
        float fr = av.x * cv.x - av.y * cv.y;
        float fi = av.x * cv.y + av.y * cv.x;
        float xr = b2f((unsigned short)hre[j >> 3][j & 7]) + fr;
        float xi = b2f((unsigned short)him[j >> 3][j & 7]) + fi;
        hr[j] = xr; hi[j] = xi;
        s0 += xr; s1 += xr * xr; s2 += xi; s3 += xi * xi;
    }
#pragma unroll
    for (int m = 1; m < 64; m <<= 1) {
        s0 += __shfl_xor(s0, m);
        s1 += __shfl_xor(s1, m);
        s2 += __shfl_xor(s2, m);
        s3 += __shfl_xor(s3, m);
    }
    float mean_r = s0 * (1.f / D_);
    float var_r  = s1 * (1.f / D_) - mean_r * mean_r;
    float mean_i = s2 * (1.f / D_);
    float var_i  = s3 * (1.f / D_) - mean_i * mean_i;
    float inv_r = 1.f / (sqrtf(fmaxf(var_r, 0.f)) + 1e-6f);
    float inv_i = 1.f / (sqrtf(fmaxf(var_i, 0.f)) + 1e-6f);

    bf16x8 pre[2], pim[2];
    pre[0] = *(const bf16x8*)(Pre + base);     pre[1] = *(const bf16x8*)(Pre + base + 8);
    pim[0] = *(const bf16x8*)(Pim + base);     pim[1] = *(const bf16x8*)(Pim + base + 8);

    float o[16];
#pragma unroll
    for (int j = 0; j < 16; j++)
        o[j] = (hr[j] - mean_r) * inv_r * b2f((unsigned short)pre[j >> 3][j & 7])
             + (hi[j] - mean_i) * inv_i * b2f((unsigned short)pim[j >> 3][j & 7]);
#pragma unroll
    for (int q = 0; q < 4; q++)
        *(float4*)(out + base + q * 4) = make_float4(o[q*4], o[q*4+1], o[q*4+2], o[q*4+3]);
}

// ---------------- launch ----------------
extern "C" void kernel_launch(void* const* d_in, const int* in_sizes, int n_in,
                              void* d_out, int out_size, void* d_ws, size_t ws_size,
                              hipStream_t stream) {
    (void)in_sizes; (void)n_in; (void)out_size;
    if (ws_size < WS_NEEDED) return;

    const float* x         = (const float*)d_in[0];
    const float* omega     = (const float*)d_in[1];
    const float* log_gamma = (const float*)d_in[2];
    const float* dt        = (const float*)d_in[3];
    const float* W_psi     = (const float*)d_in[4];
    const float* b_psi     = (const float*)d_in[5];
    const float* W_phi     = (const float*)d_in[6];
    const float* b_phi     = (const float*)d_in[7];
    const float* W_gate    = (const float*)d_in[8];
    const float* b_gate    = (const float*)d_in[9];

    char* ws = (char*)d_ws;
    __hip_bfloat16* xb   = (__hip_bfloat16*)(ws);
    __hip_bfloat16* wb   = (__hip_bfloat16*)(ws + 33554432);
    __hip_bfloat16* raw5 = (__hip_bfloat16*)(ws + 44040192);
    float2* E     = (float2*)(ws);                // overlays xb (dead after GEMM)
    float2* carry = (float2*)(ws + 4194304);
    float2* apow  = (float2*)(ws + 8388608);
    float* out = (float*)d_out;

    convert_kernel<<<2048, 256, 0, stream>>>(x, W_psi, W_phi, W_gate, (ushort*)xb, (ushort*)wb);
    gemm_kernel<<<dim3(M_ / BM, N_ / BN), 256, 0, stream>>>(xb, wb, b_psi, b_phi, b_gate, raw5);
    apow_kernel<<<128, 256, 0, stream>>>(omega, log_gamma, dt, apow);
    scan1_kernel<<<dim3(CHUNKS, B_), 256, 0, stream>>>(raw5, omega, log_gamma, dt, E);
    carry_kernel<<<B_ * D_, 128, 0, stream>>>(E, omega, log_gamma, dt, carry);
    finish_kernel<<<M_ / 4, 256, 0, stream>>>(raw5, carry, apow, out);
}